// Round 10
// baseline (175.683 us; speedup 1.0000x reference)
//
#include <hip/hip_runtime.h>
#include <hip/hip_bf16.h>
#include <hip/hip_fp16.h>

#define NN 100000
#define EE 1600000
#define FF 128
#define HH 128
#define CC 8

#define CH 8192                        // edges per chunk (phase A block)
#define NBK ((NN + 255) / 256)         // 391 coarse buckets of 256 nodes
#define NCH ((EE + CH - 1) / CH)       // 196 chunks
#define HSZ (NBK * NCH)                // 76,636 histogram entries
#define BCAP 6144                      // bucketB LDS edge capacity

typedef _Float16 half8 __attribute__((ext_vector_type(8)));
typedef float f32x4 __attribute__((ext_vector_type(4)));

// ---------------- scan kernels (no scan3: consumers fold bsum in) -----------
__global__ __launch_bounds__(1024) void k_scan1(const int* __restrict__ in,
                                                int* __restrict__ outp,
                                                int* __restrict__ bsum, int n) {
  __shared__ int sh[1024];
  int t = threadIdx.x;
  int i = blockIdx.x * 1024 + t;
  int v = (i < n) ? in[i] : 0;
  sh[t] = v;
  __syncthreads();
  for (int offs = 1; offs < 1024; offs <<= 1) {
    int add = (t >= offs) ? sh[t - offs] : 0;
    __syncthreads();
    sh[t] += add;
    __syncthreads();
  }
  if (i < n) outp[i] = sh[t] - v;  // exclusive within block
  if (t == 1023) bsum[blockIdx.x] = sh[1023];
}

__global__ __launch_bounds__(256) void k_scan2(int* __restrict__ bsum, int nb) {
  __shared__ int sh[256];
  int t = threadIdx.x;
  int v = (t < nb) ? bsum[t] : 0;
  sh[t] = v;
  __syncthreads();
  for (int offs = 1; offs < 256; offs <<= 1) {
    int add = (t >= offs) ? sh[t - offs] : 0;
    __syncthreads();
    sh[t] += add;
    __syncthreads();
  }
  if (t < nb) bsum[t] = sh[t] - v;  // exclusive
}

// ---------------- sort phase 1: per-chunk histogram over coarse buckets -----
__global__ __launch_bounds__(256) void k_histA(const int* __restrict__ dst,
                                               int* __restrict__ hist) {
  __shared__ int lh[NBK];
  int c = blockIdx.x, t = threadIdx.x;
  for (int b = t; b < NBK; b += 256) lh[b] = 0;
  __syncthreads();
  int e0 = c * CH, e1 = min(e0 + CH, EE);
  for (int j = e0 + t; j < e1; j += 256) atomicAdd(&lh[dst[j] >> 8], 1);
  __syncthreads();
  for (int b = t; b < NBK; b += 256) hist[b * NCH + c] = lh[b];
}

// ---------------- fused: scatA (blocks 0..NCH-1)  ||  gemm1 (rest) ----------
// scatA: stage[pos] = src | ((dst & 255) << 17);  hoff(i) = hist_s[i]+bsum[i>>10]
__global__ __launch_bounds__(256) void k_scat_gemm1(
    const int* __restrict__ src, const int* __restrict__ dst,
    const int* __restrict__ hist_s, const int* __restrict__ bsum,
    unsigned int* __restrict__ stage,
    const float* __restrict__ x, const float* __restrict__ W,
    __half* __restrict__ h, int n) {
  __shared__ _Float16 Wl[128 * 128];  // 32 KB (scat uses first 1564 B as int*)
  int t = threadIdx.x;

  if (blockIdx.x < NCH) {  // ---- scatter into bucketed stage ----
    int* lcur = (int*)Wl;
    int c = blockIdx.x;
    for (int b = t; b < NBK; b += 256) {
      int idx = b * NCH + c;
      lcur[b] = hist_s[idx] + bsum[idx >> 10];
    }
    __syncthreads();
    int e0 = c * CH, e1 = min(e0 + CH, EE);
    for (int j = e0 + t; j < e1; j += 256) {
      int d = dst[j];
      int pos = atomicAdd(&lcur[d >> 8], 1);
      stage[pos] = (unsigned int)src[j] | ((unsigned int)(d & 255) << 17);
    }
    return;
  }

  // ---- gemm1 ----
  {
    int c = t & 127;
    int kg0 = t >> 7;  // 0..1
    for (int kg = kg0; kg < 16; kg += 2) {
      _Float16 tmp[8];
#pragma unroll
      for (int j = 0; j < 8; ++j)
        tmp[j] = (_Float16)W[(size_t)(kg * 8 + j) * 128 + c];
      int byteoff = (c * 256 + kg * 16) ^ ((c & 7) << 4);
      *(half8*)((char*)Wl + byteoff) = *(half8*)tmp;
    }
  }
  __syncthreads();

  int row0 = (blockIdx.x - NCH) * 64;
  int w = t >> 6, l = t & 63;
  int rw = w >> 1, cw = w & 1;
  int lr = l & 15, g = l >> 4;

  f32x4 acc[2][4];
#pragma unroll
  for (int ar = 0; ar < 2; ++ar)
#pragma unroll
    for (int bt = 0; bt < 4; ++bt)
#pragma unroll
      for (int r = 0; r < 4; ++r) acc[ar][bt][r] = 0.f;

  for (int kt = 0; kt < 4; ++kt) {
    half8 a[2];
#pragma unroll
    for (int ar = 0; ar < 2; ++ar) {
      int row = row0 + rw * 32 + ar * 16 + lr;
      if (row < n) {
        const float* p = &x[(size_t)row * 128 + kt * 32 + g * 8];
        float4 v0 = *(const float4*)p;
        float4 v1 = *(const float4*)(p + 4);
        a[ar][0] = (_Float16)v0.x; a[ar][1] = (_Float16)v0.y;
        a[ar][2] = (_Float16)v0.z; a[ar][3] = (_Float16)v0.w;
        a[ar][4] = (_Float16)v1.x; a[ar][5] = (_Float16)v1.y;
        a[ar][6] = (_Float16)v1.z; a[ar][7] = (_Float16)v1.w;
      } else {
#pragma unroll
        for (int j = 0; j < 8; ++j) a[ar][j] = (_Float16)0.f;
      }
    }
#pragma unroll
    for (int bt = 0; bt < 4; ++bt) {
      int c = cw * 64 + bt * 16 + lr;
      int byteoff = (c * 256 + kt * 64 + g * 16) ^ ((c & 7) << 4);
      half8 bb = *(const half8*)((const char*)Wl + byteoff);
      acc[0][bt] = __builtin_amdgcn_mfma_f32_16x16x32_f16(a[0], bb, acc[0][bt], 0, 0, 0);
      acc[1][bt] = __builtin_amdgcn_mfma_f32_16x16x32_f16(a[1], bb, acc[1][bt], 0, 0, 0);
    }
  }

#pragma unroll
  for (int ar = 0; ar < 2; ++ar)
#pragma unroll
    for (int bt = 0; bt < 4; ++bt)
#pragma unroll
      for (int r = 0; r < 4; ++r) {
        int row = row0 + rw * 32 + ar * 16 + g * 4 + r;
        int c = cw * 64 + bt * 16 + lr;
        if (row < n) h[(size_t)row * 128 + c] = __float2half(acc[ar][bt][r]);
      }
}

// ---------------- sort phase 3: one block per 256-node bucket ---------------
// LDS-staged: bucket edges cached in LDS; histogram -> scan -> rowptr/dinv,
// then scatter to col. Global fallback if bucket exceeds BCAP.
__global__ __launch_bounds__(256) void k_bucketB(const unsigned int* __restrict__ stage,
                                                 const int* __restrict__ hist_s,
                                                 const int* __restrict__ bsum,
                                                 int* __restrict__ col,
                                                 int* __restrict__ rowptr,
                                                 float* __restrict__ dinv) {
  __shared__ unsigned int sstage[BCAP];  // 24 KB
  __shared__ int lcnt[256];
  __shared__ int lpart[256];
  int b = blockIdx.x, t = threadIdx.x;
  int n0 = b * 256;
  lcnt[t] = 0;
  int i0 = b * NCH;
  int e0 = hist_s[i0] + bsum[i0 >> 10];
  int e1;
  if (b == NBK - 1) {
    e1 = EE;
  } else {
    int i1 = (b + 1) * NCH;
    e1 = hist_s[i1] + bsum[i1 >> 10];
  }
  int cnt = e1 - e0;
  bool lds_path = (cnt <= BCAP);
  __syncthreads();
  if (lds_path) {
    for (int j = t; j < cnt; j += 256) {
      unsigned int v = stage[e0 + j];
      sstage[j] = v;
      atomicAdd(&lcnt[v >> 17], 1);
    }
  } else {
    for (int j = e0 + t; j < e1; j += 256) atomicAdd(&lcnt[stage[j] >> 17], 1);
  }
  __syncthreads();
  int c = lcnt[t];
  lpart[t] = c;
  __syncthreads();
  for (int offs = 1; offs < 256; offs <<= 1) {  // inclusive scan
    int add = (t >= offs) ? lpart[t - offs] : 0;
    __syncthreads();
    lpart[t] += add;
    __syncthreads();
  }
  int base = e0 + lpart[t] - c;  // exclusive
  int node = n0 + t;
  if (node <= NN) rowptr[node] = base;  // node==NN writes sentinel EE
  if (node < NN) dinv[node] = rsqrtf((float)c + 1.f);
  __syncthreads();
  lcnt[t] = base;  // reuse as cursors
  __syncthreads();
  if (lds_path) {
    for (int j = t; j < cnt; j += 256) {
      unsigned int v = sstage[j];
      int pos = atomicAdd(&lcnt[v >> 17], 1);
      col[pos] = (int)(v & 0x1FFFFu);
    }
  } else {
    for (int j = e0 + t; j < e1; j += 256) {
      unsigned int v = stage[j];
      int pos = atomicAdd(&lcnt[v >> 17], 1);
      col[pos] = (int)(v & 0x1FFFFu);
    }
  }
}

// ---------------- Agg1: out = relu(Anorm @ h + b1), wave per node, fp16 ----
// 16 edges batched -> 16 h-row gathers + 16 dinv gathers in flight.
__global__ __launch_bounds__(256) void k_agg1(const __half* __restrict__ h,
                                              const int* __restrict__ rowptr,
                                              const int* __restrict__ col,
                                              const float* __restrict__ dinv,
                                              const float* __restrict__ b1,
                                              __half2* __restrict__ out, int n) {
  int wid = threadIdx.x >> 6;
  int lane = threadIdx.x & 63;
  int node = blockIdx.x * 4 + wid;
  if (node >= n) return;
  float dn = dinv[node];
  const __half2* hp = (const __half2*)h;
  float2 acc = make_float2(0.f, 0.f);
  int e0 = rowptr[node], e1 = rowptr[node + 1];
  int e = e0;
  for (; e + 15 < e1; e += 16) {
    int s[16];
#pragma unroll
    for (int u = 0; u < 16; ++u) s[u] = col[e + u];
    float w[16];
    __half2 f[16];
#pragma unroll
    for (int u = 0; u < 16; ++u) w[u] = dinv[s[u]];
#pragma unroll
    for (int u = 0; u < 16; ++u) f[u] = hp[(size_t)s[u] * 64 + lane];
#pragma unroll
    for (int u = 0; u < 16; ++u) {
      float2 ff = __half22float2(f[u]);
      float ww = w[u] * dn;
      acc.x = fmaf(ww, ff.x, acc.x);
      acc.y = fmaf(ww, ff.y, acc.y);
    }
  }
  for (; e + 3 < e1; e += 4) {
    int s[4];
#pragma unroll
    for (int u = 0; u < 4; ++u) s[u] = col[e + u];
    float w[4];
    __half2 f[4];
#pragma unroll
    for (int u = 0; u < 4; ++u) w[u] = dinv[s[u]];
#pragma unroll
    for (int u = 0; u < 4; ++u) f[u] = hp[(size_t)s[u] * 64 + lane];
#pragma unroll
    for (int u = 0; u < 4; ++u) {
      float2 ff = __half22float2(f[u]);
      float ww = w[u] * dn;
      acc.x = fmaf(ww, ff.x, acc.x);
      acc.y = fmaf(ww, ff.y, acc.y);
    }
  }
  for (; e < e1; ++e) {
    int s = col[e];
    float w = dinv[s] * dn;
    float2 f = __half22float2(hp[(size_t)s * 64 + lane]);
    acc.x = fmaf(w, f.x, acc.x);
    acc.y = fmaf(w, f.y, acc.y);
  }
  {  // self loop
    float w = dn * dn;
    float2 f = __half22float2(hp[(size_t)node * 64 + lane]);
    acc.x = fmaf(w, f.x, acc.x);
    acc.y = fmaf(w, f.y, acc.y);
  }
  float2 bb = ((const float2*)b1)[lane];
  acc.x = fmaxf(acc.x + bb.x, 0.f);
  acc.y = fmaxf(acc.y + bb.y, 0.f);
  out[(size_t)node * 64 + lane] = __floats2half2_rn(acc.x, acc.y);
}

// ---------------- GEMM2: h2 = a @ W2 (fp16 in, fp16 out), thread per row ---
__global__ __launch_bounds__(256) void k_gemm2(const __half* __restrict__ a,
                                               const float* __restrict__ W2,
                                               __half* __restrict__ h2, int n) {
  int r = blockIdx.x * 256 + threadIdx.x;
  if (r >= n) return;
  float acc[8];
#pragma unroll
  for (int c = 0; c < 8; ++c) acc[c] = 0.f;
  const __half2* ap = (const __half2*)(a + (size_t)r * 128);
#pragma unroll 8
  for (int k2 = 0; k2 < 64; ++k2) {
    float2 v = __half22float2(ap[k2]);
    int k = k2 * 2;
#pragma unroll
    for (int c = 0; c < 8; ++c) {
      acc[c] = fmaf(v.x, W2[(k + 0) * 8 + c], acc[c]);
      acc[c] = fmaf(v.y, W2[(k + 1) * 8 + c], acc[c]);
    }
  }
  union { __half2 h2v[4]; uint4 u; } pk;
#pragma unroll
  for (int c = 0; c < 4; ++c)
    pk.h2v[c] = __floats2half2_rn(acc[2 * c], acc[2 * c + 1]);
  *(uint4*)&h2[(size_t)r * 8] = pk.u;
}

// ---------------- Agg2: out = Anorm @ h2 + b2, 8 threads per node ----------
__global__ __launch_bounds__(256) void k_agg2(const __half* __restrict__ h2,
                                              const int* __restrict__ rowptr,
                                              const int* __restrict__ col,
                                              const float* __restrict__ dinv,
                                              const float* __restrict__ b2,
                                              float* __restrict__ out, int n) {
  int gthread = blockIdx.x * 256 + threadIdx.x;
  int node = gthread >> 3, f = gthread & 7;
  if (node >= n) return;
  float dn = dinv[node];
  float acc = 0.f;
  int e0 = rowptr[node], e1 = rowptr[node + 1];
  int e = e0;
  for (; e + 7 < e1; e += 8) {
    int s[8];
#pragma unroll
    for (int u = 0; u < 8; ++u) s[u] = col[e + u];
    float w[8];
    float v[8];
#pragma unroll
    for (int u = 0; u < 8; ++u) w[u] = dinv[s[u]];
#pragma unroll
    for (int u = 0; u < 8; ++u) v[u] = __half2float(h2[(size_t)s[u] * 8 + f]);
#pragma unroll
    for (int u = 0; u < 8; ++u) acc = fmaf(w[u] * dn, v[u], acc);
  }
  for (; e < e1; ++e) {
    int s = col[e];
    acc = fmaf(dinv[s] * dn, __half2float(h2[(size_t)s * 8 + f]), acc);
  }
  acc = fmaf(dn * dn, __half2float(h2[(size_t)node * 8 + f]), acc);
  out[(size_t)node * 8 + f] = acc + b2[f];
}

extern "C" void kernel_launch(void* const* d_in, const int* in_sizes, int n_in,
                              void* d_out, int out_size, void* d_ws, size_t ws_size,
                              hipStream_t stream) {
  const float* x  = (const float*)d_in[0];
  const int* eidx = (const int*)d_in[1];
  const float* W1 = (const float*)d_in[2];
  const float* b1 = (const float*)d_in[3];
  const float* W2 = (const float*)d_in[4];
  const float* b2 = (const float*)d_in[5];
  float* out = (float*)d_out;
  const int* src = eidx;
  const int* dst = eidx + EE;

  char* ws = (char*)d_ws;
  size_t off = 0;
  auto alloc = [&](size_t bytes) -> char* {
    char* p = ws + off;
    off = (off + bytes + 255) & ~(size_t)255;
    return p;
  };

  float*        dinv   = (float*)       alloc((size_t)NN * 4);
  int*          rowptr = (int*)         alloc((size_t)(NN + 1) * 4);
  int*          bsum   = (int*)         alloc(1024 * 4);
  int*          hist_g = (int*)         alloc((size_t)HSZ * 4);
  int*          hist_s = (int*)         alloc((size_t)HSZ * 4);
  unsigned int* stage  = (unsigned int*)alloc((size_t)EE * 4);
  int*          colbuf = (int*)         alloc((size_t)EE * 4);
  __half*       h1     = (__half*)      alloc((size_t)NN * HH * 2);
  __half2*      agg1   = (__half2*)     alloc((size_t)NN * HH * 2);
  __half*       h2     = (__half*)h1;  // reuse: h1 dead after agg1

  int nbScanH = (HSZ + 1023) / 1024;  // 75

  // counting sort by dst (no global atomics); bucketB derives rowptr + dinv
  k_histA<<<NCH, 256, 0, stream>>>(dst, hist_g);
  k_scan1<<<nbScanH, 1024, 0, stream>>>(hist_g, hist_s, bsum, HSZ);
  k_scan2<<<1, 256, 0, stream>>>(bsum, nbScanH);

  // scatA || gemm1 fused (independent work, one dispatch)
  int nbG1 = (NN + 63) / 64;
  k_scat_gemm1<<<NCH + nbG1, 256, 0, stream>>>(src, dst, hist_s, bsum, stage,
                                               x, W1, h1, NN);
  k_bucketB<<<NBK, 256, 0, stream>>>(stage, hist_s, bsum, colbuf, rowptr, dinv);

  k_agg1<<<(NN + 3) / 4, 256, 0, stream>>>(h1, rowptr, colbuf, dinv, b1, agg1, NN);
  k_gemm2<<<(NN + 255) / 256, 256, 0, stream>>>((const __half*)agg1, W2, h2, NN);
  k_agg2<<<(NN * 8 + 255) / 256, 256, 0, stream>>>(h2, rowptr, colbuf, dinv,
                                                   b2, out, NN);
}

// Round 11
// 165.828 us; speedup vs baseline: 1.0594x; 1.0594x over previous
//
#include <hip/hip_runtime.h>
#include <hip/hip_bf16.h>
#include <hip/hip_fp16.h>

#define NN 100000
#define EE 1600000
#define FF 128
#define HH 128
#define CC 8

#define CH 8192                        // edges per chunk (phase A block)
#define NBK ((NN + 255) / 256)         // 391 coarse buckets of 256 nodes
#define NCH ((EE + CH - 1) / CH)       // 196 chunks
#define HSZ (NBK * NCH)                // 76,636 histogram entries

typedef _Float16 half8 __attribute__((ext_vector_type(8)));
typedef float f32x4 __attribute__((ext_vector_type(4)));

// ---------------- scan kernels (no scan3: consumers fold bsum in) -----------
__global__ __launch_bounds__(1024) void k_scan1(const int* __restrict__ in,
                                                int* __restrict__ outp,
                                                int* __restrict__ bsum, int n) {
  __shared__ int sh[1024];
  int t = threadIdx.x;
  int i = blockIdx.x * 1024 + t;
  int v = (i < n) ? in[i] : 0;
  sh[t] = v;
  __syncthreads();
  for (int offs = 1; offs < 1024; offs <<= 1) {
    int add = (t >= offs) ? sh[t - offs] : 0;
    __syncthreads();
    sh[t] += add;
    __syncthreads();
  }
  if (i < n) outp[i] = sh[t] - v;  // exclusive within block
  if (t == 1023) bsum[blockIdx.x] = sh[1023];
}

__global__ __launch_bounds__(256) void k_scan2(int* __restrict__ bsum, int nb) {
  __shared__ int sh[256];
  int t = threadIdx.x;
  int v = (t < nb) ? bsum[t] : 0;
  sh[t] = v;
  __syncthreads();
  for (int offs = 1; offs < 256; offs <<= 1) {
    int add = (t >= offs) ? sh[t - offs] : 0;
    __syncthreads();
    sh[t] += add;
    __syncthreads();
  }
  if (t < nb) bsum[t] = sh[t] - v;  // exclusive
}

// ---------------- sort phase 1: per-chunk histogram over coarse buckets -----
__global__ __launch_bounds__(256) void k_histA(const int* __restrict__ dst,
                                               int* __restrict__ hist) {
  __shared__ int lh[NBK];
  int c = blockIdx.x, t = threadIdx.x;
  for (int b = t; b < NBK; b += 256) lh[b] = 0;
  __syncthreads();
  int e0 = c * CH, e1 = min(e0 + CH, EE);
  for (int j = e0 + t; j < e1; j += 256) atomicAdd(&lh[dst[j] >> 8], 1);
  __syncthreads();
  for (int b = t; b < NBK; b += 256) hist[b * NCH + c] = lh[b];
}

// ---------------- fused: scatA (blocks 0..NCH-1)  ||  gemm1 (rest) ----------
// scatA: stage[pos] = src | ((dst & 255) << 17);  hoff(i) = hist_s[i]+bsum[i>>10]
__global__ __launch_bounds__(256) void k_scat_gemm1(
    const int* __restrict__ src, const int* __restrict__ dst,
    const int* __restrict__ hist_s, const int* __restrict__ bsum,
    unsigned int* __restrict__ stage,
    const float* __restrict__ x, const float* __restrict__ W,
    __half* __restrict__ h, int n) {
  __shared__ _Float16 Wl[128 * 128];  // 32 KB (scat uses first 1564 B as int*)
  int t = threadIdx.x;

  if (blockIdx.x < NCH) {  // ---- scatter into bucketed stage ----
    int* lcur = (int*)Wl;
    int c = blockIdx.x;
    for (int b = t; b < NBK; b += 256) {
      int idx = b * NCH + c;
      lcur[b] = hist_s[idx] + bsum[idx >> 10];
    }
    __syncthreads();
    int e0 = c * CH, e1 = min(e0 + CH, EE);
    for (int j = e0 + t; j < e1; j += 256) {
      int d = dst[j];
      int pos = atomicAdd(&lcur[d >> 8], 1);
      stage[pos] = (unsigned int)src[j] | ((unsigned int)(d & 255) << 17);
    }
    return;
  }

  // ---- gemm1 ----
  {
    int c = t & 127;
    int kg0 = t >> 7;  // 0..1
    for (int kg = kg0; kg < 16; kg += 2) {
      _Float16 tmp[8];
#pragma unroll
      for (int j = 0; j < 8; ++j)
        tmp[j] = (_Float16)W[(size_t)(kg * 8 + j) * 128 + c];
      int byteoff = (c * 256 + kg * 16) ^ ((c & 7) << 4);
      *(half8*)((char*)Wl + byteoff) = *(half8*)tmp;
    }
  }
  __syncthreads();

  int row0 = (blockIdx.x - NCH) * 64;
  int w = t >> 6, l = t & 63;
  int rw = w >> 1, cw = w & 1;
  int lr = l & 15, g = l >> 4;

  f32x4 acc[2][4];
#pragma unroll
  for (int ar = 0; ar < 2; ++ar)
#pragma unroll
    for (int bt = 0; bt < 4; ++bt)
#pragma unroll
      for (int r = 0; r < 4; ++r) acc[ar][bt][r] = 0.f;

  for (int kt = 0; kt < 4; ++kt) {
    half8 a[2];
#pragma unroll
    for (int ar = 0; ar < 2; ++ar) {
      int row = row0 + rw * 32 + ar * 16 + lr;
      if (row < n) {
        const float* p = &x[(size_t)row * 128 + kt * 32 + g * 8];
        float4 v0 = *(const float4*)p;
        float4 v1 = *(const float4*)(p + 4);
        a[ar][0] = (_Float16)v0.x; a[ar][1] = (_Float16)v0.y;
        a[ar][2] = (_Float16)v0.z; a[ar][3] = (_Float16)v0.w;
        a[ar][4] = (_Float16)v1.x; a[ar][5] = (_Float16)v1.y;
        a[ar][6] = (_Float16)v1.z; a[ar][7] = (_Float16)v1.w;
      } else {
#pragma unroll
        for (int j = 0; j < 8; ++j) a[ar][j] = (_Float16)0.f;
      }
    }
#pragma unroll
    for (int bt = 0; bt < 4; ++bt) {
      int c = cw * 64 + bt * 16 + lr;
      int byteoff = (c * 256 + kt * 64 + g * 16) ^ ((c & 7) << 4);
      half8 bb = *(const half8*)((const char*)Wl + byteoff);
      acc[0][bt] = __builtin_amdgcn_mfma_f32_16x16x32_f16(a[0], bb, acc[0][bt], 0, 0, 0);
      acc[1][bt] = __builtin_amdgcn_mfma_f32_16x16x32_f16(a[1], bb, acc[1][bt], 0, 0, 0);
    }
  }

#pragma unroll
  for (int ar = 0; ar < 2; ++ar)
#pragma unroll
    for (int bt = 0; bt < 4; ++bt)
#pragma unroll
      for (int r = 0; r < 4; ++r) {
        int row = row0 + rw * 32 + ar * 16 + g * 4 + r;
        int c = cw * 64 + bt * 16 + lr;
        if (row < n) h[(size_t)row * 128 + c] = __float2half(acc[ar][bt][r]);
      }
}

// ---------------- sort phase 3: one block per 256-node bucket ---------------
// Pass 1: LDS histogram -> LDS scan -> rowptr + dinv. Pass 2: scatter col.
__global__ __launch_bounds__(256) void k_bucketB(const unsigned int* __restrict__ stage,
                                                 const int* __restrict__ hist_s,
                                                 const int* __restrict__ bsum,
                                                 int* __restrict__ col,
                                                 int* __restrict__ rowptr,
                                                 float* __restrict__ dinv) {
  __shared__ int lcnt[256];
  __shared__ int lpart[256];
  int b = blockIdx.x, t = threadIdx.x;
  int n0 = b * 256;
  lcnt[t] = 0;
  int i0 = b * NCH;
  int e0 = hist_s[i0] + bsum[i0 >> 10];
  int e1;
  if (b == NBK - 1) {
    e1 = EE;
  } else {
    int i1 = (b + 1) * NCH;
    e1 = hist_s[i1] + bsum[i1 >> 10];
  }
  __syncthreads();
  for (int j = e0 + t; j < e1; j += 256)
    atomicAdd(&lcnt[stage[j] >> 17], 1);
  __syncthreads();
  int c = lcnt[t];
  lpart[t] = c;
  __syncthreads();
  for (int offs = 1; offs < 256; offs <<= 1) {  // inclusive scan
    int add = (t >= offs) ? lpart[t - offs] : 0;
    __syncthreads();
    lpart[t] += add;
    __syncthreads();
  }
  int base = e0 + lpart[t] - c;  // exclusive
  int node = n0 + t;
  if (node <= NN) rowptr[node] = base;  // node==NN writes sentinel EE
  if (node < NN) dinv[node] = rsqrtf((float)c + 1.f);
  __syncthreads();
  lcnt[t] = base;  // reuse as cursors
  __syncthreads();
  for (int j = e0 + t; j < e1; j += 256) {
    unsigned int v = stage[j];
    int pos = atomicAdd(&lcnt[v >> 17], 1);
    col[pos] = (int)(v & 0x1FFFFu);
  }
}

// ---------------- Agg1 + fused GEMM2: h2 = relu(Anorm@h + b1) @ W2 ---------
// Wave per node, MLP-8 gather loop (proven 74us). Epilogue: fp32 row -> LDS,
// each lane dots 16 k-elems vs L1-hot W2, 3-step shfl_xor reduce, lanes 0-7
// store h2. No persistent W2 registers (R8 lesson), no agg1 buffer round trip.
__global__ __launch_bounds__(256) void k_agg1g(const __half* __restrict__ h,
                                               const int* __restrict__ rowptr,
                                               const int* __restrict__ col,
                                               const float* __restrict__ dinv,
                                               const float* __restrict__ b1,
                                               const float* __restrict__ W2,
                                               __half* __restrict__ h2, int n) {
  __shared__ float arow[4][128];
  int wid = threadIdx.x >> 6;
  int lane = threadIdx.x & 63;
  int node = blockIdx.x * 4 + wid;
  if (node >= n) return;
  float dn = dinv[node];
  const __half2* hp = (const __half2*)h;
  float2 acc = make_float2(0.f, 0.f);
  int e0 = rowptr[node], e1 = rowptr[node + 1];
  int e = e0;
  for (; e + 7 < e1; e += 8) {
    int s[8];
#pragma unroll
    for (int u = 0; u < 8; ++u) s[u] = col[e + u];
    float w[8];
    __half2 f[8];
#pragma unroll
    for (int u = 0; u < 8; ++u) w[u] = dinv[s[u]];
#pragma unroll
    for (int u = 0; u < 8; ++u) f[u] = hp[(size_t)s[u] * 64 + lane];
#pragma unroll
    for (int u = 0; u < 8; ++u) {
      float2 ff = __half22float2(f[u]);
      float ww = w[u] * dn;
      acc.x = fmaf(ww, ff.x, acc.x);
      acc.y = fmaf(ww, ff.y, acc.y);
    }
  }
  for (; e + 1 < e1; e += 2) {
    int s0 = col[e], s1 = col[e + 1];
    float w0 = dinv[s0] * dn, w1 = dinv[s1] * dn;
    float2 f0 = __half22float2(hp[(size_t)s0 * 64 + lane]);
    float2 f1 = __half22float2(hp[(size_t)s1 * 64 + lane]);
    acc.x = fmaf(w0, f0.x, acc.x); acc.y = fmaf(w0, f0.y, acc.y);
    acc.x = fmaf(w1, f1.x, acc.x); acc.y = fmaf(w1, f1.y, acc.y);
  }
  if (e < e1) {
    int s = col[e];
    float w = dinv[s] * dn;
    float2 f = __half22float2(hp[(size_t)s * 64 + lane]);
    acc.x = fmaf(w, f.x, acc.x);
    acc.y = fmaf(w, f.y, acc.y);
  }
  {  // self loop
    float w = dn * dn;
    float2 f = __half22float2(hp[(size_t)node * 64 + lane]);
    acc.x = fmaf(w, f.x, acc.x);
    acc.y = fmaf(w, f.y, acc.y);
  }
  float2 bb = ((const float2*)b1)[lane];
  acc.x = fmaxf(acc.x + bb.x, 0.f);
  acc.y = fmaxf(acc.y + bb.y, 0.f);

  // ---- fused gemm2 epilogue (wave-local; LDS ops in-order within a wave) ----
  *(float2*)&arow[wid][2 * lane] = acc;
  asm volatile("" ::: "memory");  // keep LDS write before reads
  int colc = lane & 7;  // output column
  int kg = lane >> 3;   // k-group: covers k = kg*16 .. kg*16+15
  float p = 0.f;
#pragma unroll
  for (int j = 0; j < 16; ++j) {
    int k = kg * 16 + j;
    p = fmaf(arow[wid][k], W2[k * 8 + colc], p);
  }
  p += __shfl_xor(p, 8);
  p += __shfl_xor(p, 16);
  p += __shfl_xor(p, 32);
  if (lane < 8) h2[(size_t)node * 8 + colc] = __float2half(p);
}

// ---------------- Agg2: out = Anorm @ h2 + b2, 8 threads per node ----------
__global__ __launch_bounds__(256) void k_agg2(const __half* __restrict__ h2,
                                              const int* __restrict__ rowptr,
                                              const int* __restrict__ col,
                                              const float* __restrict__ dinv,
                                              const float* __restrict__ b2,
                                              float* __restrict__ out, int n) {
  int gthread = blockIdx.x * 256 + threadIdx.x;
  int node = gthread >> 3, f = gthread & 7;
  if (node >= n) return;
  float dn = dinv[node];
  float acc = 0.f;
  int e0 = rowptr[node], e1 = rowptr[node + 1];
  int e = e0;
  for (; e + 7 < e1; e += 8) {
    int s[8];
#pragma unroll
    for (int u = 0; u < 8; ++u) s[u] = col[e + u];
    float w[8];
    float v[8];
#pragma unroll
    for (int u = 0; u < 8; ++u) w[u] = dinv[s[u]];
#pragma unroll
    for (int u = 0; u < 8; ++u) v[u] = __half2float(h2[(size_t)s[u] * 8 + f]);
#pragma unroll
    for (int u = 0; u < 8; ++u) acc = fmaf(w[u] * dn, v[u], acc);
  }
  for (; e < e1; ++e) {
    int s = col[e];
    acc = fmaf(dinv[s] * dn, __half2float(h2[(size_t)s * 8 + f]), acc);
  }
  acc = fmaf(dn * dn, __half2float(h2[(size_t)node * 8 + f]), acc);
  out[(size_t)node * 8 + f] = acc + b2[f];
}

extern "C" void kernel_launch(void* const* d_in, const int* in_sizes, int n_in,
                              void* d_out, int out_size, void* d_ws, size_t ws_size,
                              hipStream_t stream) {
  const float* x  = (const float*)d_in[0];
  const int* eidx = (const int*)d_in[1];
  const float* W1 = (const float*)d_in[2];
  const float* b1 = (const float*)d_in[3];
  const float* W2 = (const float*)d_in[4];
  const float* b2 = (const float*)d_in[5];
  float* out = (float*)d_out;
  const int* src = eidx;
  const int* dst = eidx + EE;

  char* ws = (char*)d_ws;
  size_t off = 0;
  auto alloc = [&](size_t bytes) -> char* {
    char* p = ws + off;
    off = (off + bytes + 255) & ~(size_t)255;
    return p;
  };

  float*        dinv   = (float*)       alloc((size_t)NN * 4);
  int*          rowptr = (int*)         alloc((size_t)(NN + 1) * 4);
  int*          bsum   = (int*)         alloc(1024 * 4);
  int*          hist_g = (int*)         alloc((size_t)HSZ * 4);
  int*          hist_s = (int*)         alloc((size_t)HSZ * 4);
  unsigned int* stage  = (unsigned int*)alloc((size_t)EE * 4);
  int*          colbuf = (int*)         alloc((size_t)EE * 4);
  __half*       h1     = (__half*)      alloc((size_t)NN * HH * 2);
  __half*       h2     = (__half*)      alloc((size_t)NN * CC * 2);

  int nbScanH = (HSZ + 1023) / 1024;  // 75

  // counting sort by dst (no global atomics); bucketB derives rowptr + dinv
  k_histA<<<NCH, 256, 0, stream>>>(dst, hist_g);
  k_scan1<<<nbScanH, 1024, 0, stream>>>(hist_g, hist_s, bsum, HSZ);
  k_scan2<<<1, 256, 0, stream>>>(bsum, nbScanH);

  // scatA || gemm1 fused (independent work, one dispatch)
  int nbG1 = (NN + 63) / 64;
  k_scat_gemm1<<<NCH + nbG1, 256, 0, stream>>>(src, dst, hist_s, bsum, stage,
                                               x, W1, h1, NN);
  k_bucketB<<<NBK, 256, 0, stream>>>(stage, hist_s, bsum, colbuf, rowptr, dinv);

  k_agg1g<<<(NN + 3) / 4, 256, 0, stream>>>(h1, rowptr, colbuf, dinv, b1, W2,
                                            h2, NN);
  k_agg2<<<(NN * 8 + 255) / 256, 256, 0, stream>>>(h2, rowptr, colbuf, dinv,
                                                   b2, out, NN);
}